// Round 1
// baseline (631.329 us; speedup 1.0000x reference)
//
#include <hip/hip_runtime.h>

// ---------------------------------------------------------------------------
// Attention_81449759801699 on MI355X (gfx950)
// Pipeline: prep(weights fold+transpose bf16, text pad, bias table)
//        -> gemm<1> kv-proj -> gemm<0> q-proj
//        -> 4x { attn (scores+softmax+PV+gelu) ; gemm<2> proj }
// All matmuls: v_mfma_f32_16x16x32_bf16, fp32 accumulate.
// Workspace usage ~78 MB.
// ---------------------------------------------------------------------------

typedef unsigned short u16;
typedef unsigned int u32;
typedef float  f32x4  __attribute__((ext_vector_type(4)));
typedef float  fl4    __attribute__((ext_vector_type(4)));
typedef short  short8 __attribute__((ext_vector_type(8)));
typedef u32    u32x4  __attribute__((ext_vector_type(4)));
typedef u32    u32x2  __attribute__((ext_vector_type(2)));

#define EPSF 1e-5f
#define NH 8
#define NTP 416                       // 400 text tokens padded to 416 (13*32)
#define SSTR 440                      // S row stride (bf16 elems), banks <=2-way
#define ATTN_LDS (64*SSTR*2 + 16384 + 512)

static __device__ __forceinline__ u16 f2bf(float f){
  u32 u = __builtin_bit_cast(u32, f);
  u += 0x7FFFu + ((u >> 16) & 1u);    // RNE (finite inputs only)
  return (u16)(u >> 16);
}
static __device__ __forceinline__ float bf2f(u16 b){
  u32 u = ((u32)b) << 16;
  return __builtin_bit_cast(float, u);
}
static __device__ __forceinline__ f32x4 mfma16(short8 a, short8 b, f32x4 c){
  return __builtin_amdgcn_mfma_f32_16x16x32_bf16(a, b, c, 0, 0, 0);
}
static __device__ __forceinline__ void gld16(const void* g, void* l){
  __builtin_amdgcn_global_load_lds(
      (const __attribute__((address_space(1))) u32*)g,
      (__attribute__((address_space(3))) u32*)l, 16, 0, 0);
}

// ---------------------------------------------------------------------------
// Weight convert: wT[c][r] = bf16(w[r][c] * gamma[c]*rsqrt(var[c]+eps))
// 64x64 LDS tile transpose; grid (C/64, R/64)
// ---------------------------------------------------------------------------
__global__ __launch_bounds__(256) void wconv_kernel(
    const float* __restrict__ w, const float* __restrict__ gamma,
    const float* __restrict__ var, u16* __restrict__ wT, int R, int C)
{
  __shared__ u16 tile[64*65];
  const int tx = blockIdx.x, ty = blockIdx.y, tid = threadIdx.x;
  #pragma unroll
  for (int i = 0; i < 16; ++i){
    int lin = tid + i*256;
    int rr = lin >> 6, cc = lin & 63;
    int c = tx*64 + cc;
    float s = gamma[c] * rsqrtf(var[c] + EPSF);
    tile[rr*65 + cc] = f2bf(w[(size_t)(ty*64 + rr)*C + c] * s);
  }
  __syncthreads();
  #pragma unroll
  for (int i = 0; i < 16; ++i){
    int lin = tid + i*256;
    int cc = lin >> 6, rr = lin & 63;
    wT[(size_t)(tx*64 + cc)*R + ty*64 + rr] = tile[rr*65 + cc];
  }
}

// text -> bf16, padded to 512 rows (rows >=400 zero). grid 1024 x 256
__global__ __launch_bounds__(256) void textconv_kernel(
    const float* __restrict__ text, u16* __restrict__ tbf)
{
  int idx = blockIdx.x*256 + threadIdx.x;   // 512*512
  int r = idx >> 9, c = idx & 511;
  float v = (r < 400) ? text[r*512 + c] : 0.f;
  tbf[idx] = f2bf(v);
}

// bias table: btab[h][n][t] bf16; t>=400 -> -1e30 (mask). grid 13312 x 256
__global__ __launch_bounds__(256) void bias_kernel(
    const float* __restrict__ ab, u16* __restrict__ btab)
{
  int idx = blockIdx.x*256 + threadIdx.x;   // 8*1024*416
  int t = idx % 416;
  int n = (idx / 416) & 1023;
  int h = idx / (416*1024);
  float v;
  if (t >= 400) v = -1e30f;
  else {
    int i = n >> 5, j = n & 31;
    int a = t / 100, bb = t % 100;
    v = ab[h*10000 + abs(i - a)*100 + abs(j - bb)];
  }
  btab[idx] = f2bf(v);
}

// ---------------------------------------------------------------------------
// 128x128 tile GEMM (m97 structure). BT is [N][K] bf16 (BN scale folded).
// MODE 0: A=x fp32 (reg-stage cvt) -> q_ws[b][h][n][64] bf16, *0.125 folded
// MODE 1: A=text_bf -> K_ws[h][t][64], V_ws[h][dv][t] bf16 (t<416 guard)
// MODE 2: A=a_ws bf16 -> d_out fp32 (+BN shift), rows offset row_base
// ---------------------------------------------------------------------------
template<int MODE>
__global__ __launch_bounds__(256) void gemm_kernel(
    const void* __restrict__ Ap, const u16* __restrict__ BT,
    const float* __restrict__ g1, const float* __restrict__ b1,
    const float* __restrict__ m1, const float* __restrict__ v1,
    void* __restrict__ o0, void* __restrict__ o1, int K, int row_base)
{
  __shared__ u16 lds[8192];                 // A [0,4096), B [4096,8192)
  const int tid = threadIdx.x;
  const int cb = blockIdx.x, rb = blockIdx.y;
  const int lane = tid & 63, wid = tid >> 6;
  const int lg = lane >> 4, lc = lane & 15;
  const int wr = wid >> 1, wc = wid & 1;
  const int row0 = rb*128, col0 = cb*128;
  f32x4 acc[4][4] = {};
  const int nkb = K >> 5;

  for (int kb = 0; kb < nkb; ++kb){
    if (MODE == 0){
      const float* A = (const float*)Ap;
      #pragma unroll
      for (int it = 0; it < 4; ++it){
        int lin = tid + it*256;
        int row = lin >> 3, c4 = lin & 7;
        const fl4 v = *(const fl4*)(A + (size_t)(row0 + row)*K + kb*32 + c4*4);
        u32x2 p;
        p[0] = (u32)f2bf(v[0]) | ((u32)f2bf(v[1]) << 16);
        p[1] = (u32)f2bf(v[2]) | ((u32)f2bf(v[3]) << 16);
        *(u32x2*)&lds[row*32 + c4*4] = p;
      }
    } else {
      const u16* A = (const u16*)Ap;
      #pragma unroll
      for (int it = 0; it < 2; ++it){
        int lin = tid + it*256;
        int row = lin >> 2, seg = lin & 3;
        gld16(A + (size_t)(row0 + row)*K + kb*32 + seg*8, &lds[lin*8]);
      }
    }
    #pragma unroll
    for (int it = 0; it < 2; ++it){
      int lin = tid + it*256;
      int col = lin >> 2, seg = lin & 3;
      gld16(BT + (size_t)(col0 + col)*K + kb*32 + seg*8, &lds[4096 + lin*8]);
    }
    __syncthreads();
    short8 af[4], bfr[4];
    #pragma unroll
    for (int rt = 0; rt < 4; ++rt)
      af[rt] = *(const short8*)&lds[(wr*64 + rt*16 + lc)*32 + lg*8];
    #pragma unroll
    for (int ct = 0; ct < 4; ++ct)
      bfr[ct] = *(const short8*)&lds[4096 + (wc*64 + ct*16 + lc)*32 + lg*8];
    #pragma unroll
    for (int rt = 0; rt < 4; ++rt)
      #pragma unroll
      for (int ct = 0; ct < 4; ++ct)
        acc[rt][ct] = mfma16(af[rt], bfr[ct], acc[rt][ct]);
    __syncthreads();
  }

  if (MODE == 0){
    u16* qws = (u16*)o0;
    #pragma unroll
    for (int ct = 0; ct < 4; ++ct){
      int c = col0 + wc*64 + ct*16 + lc;
      float sc = g1[c] * rsqrtf(v1[c] + EPSF);
      float sh = (b1[c] - m1[c]*sc) * 0.125f;   // 1/sqrt(64) fold
      int h = c >> 6, dk = c & 63;
      #pragma unroll
      for (int rt = 0; rt < 4; ++rt)
        #pragma unroll
        for (int r = 0; r < 4; ++r){
          int mr = row0 + wr*64 + rt*16 + lg*4 + r;
          int b = mr >> 10, n = mr & 1023;
          qws[(size_t)((b*NH + h)*1024 + n)*64 + dk] =
              f2bf(acc[rt][ct][r]*0.125f + sh);
        }
    }
  } else if (MODE == 1){
    u16* Kw = (u16*)o0; u16* Vw = (u16*)o1;
    #pragma unroll
    for (int ct = 0; ct < 4; ++ct){
      int c = col0 + wc*64 + ct*16 + lc;
      float sc = g1[c] * rsqrtf(v1[c] + EPSF);
      float sh = b1[c] - m1[c]*sc;
      int h = c / 320, sub = c % 320;
      #pragma unroll
      for (int rt = 0; rt < 4; ++rt)
        #pragma unroll
        for (int r = 0; r < 4; ++r){
          int t = row0 + wr*64 + rt*16 + lg*4 + r;
          if (t < NTP){
            u16 val = f2bf(acc[rt][ct][r] + sh);
            if (sub < 64) Kw[(size_t)(h*NTP + t)*64 + sub] = val;
            else          Vw[(size_t)(h*256 + (sub - 64))*NTP + t] = val;
          }
        }
    }
  } else {
    float* outp = (float*)o0;
    #pragma unroll
    for (int ct = 0; ct < 4; ++ct){
      int c = col0 + wc*64 + ct*16 + lc;
      float sc = g1[c] * rsqrtf(v1[c] + EPSF);
      float sh = b1[c] - m1[c]*sc;
      #pragma unroll
      for (int rt = 0; rt < 4; ++rt)
        #pragma unroll
        for (int r = 0; r < 4; ++r){
          int mr = row_base + row0 + wr*64 + rt*16 + lg*4 + r;
          outp[(size_t)mr*512 + c] = acc[rt][ct][r] + sh;
        }
    }
  }
}

// ---------------------------------------------------------------------------
// Attention: WG = (64 q-rows, h, b). 4 waves; wave owns 16 rows for S/softmax.
// S bf16 in LDS [64][440]; K/V chunk-staged (16KB, XOR swizzle row&7<<4).
// PV reads P straight out of S as MFMA A-frags. GELU fused in epilogue.
// LDS 73216 B -> 2 WGs/CU.
// ---------------------------------------------------------------------------
__global__ __launch_bounds__(256) void attn_kernel(
    const u16* __restrict__ qws, const u16* __restrict__ Kw,
    const u16* __restrict__ Vw, const u16* __restrict__ btab,
    u16* __restrict__ aws, int b_base)
{
  extern __shared__ char smem[];
  u16*   S    = (u16*)smem;                        // [64][SSTR]
  char*  kvb  = smem + 64*SSTR*2;                  // 16 KiB K/V staging
  float* mrow = (float*)(smem + 64*SSTR*2 + 16384);
  float* lrow = mrow + 64;

  const int tid = threadIdx.x;
  const int lane = tid & 63, wid = tid >> 6;
  const int lg = lane >> 4, lc = lane & 15;
  const int qt = blockIdx.x, h = blockIdx.y, bz = blockIdx.z;
  const int b = b_base + bz;
  const int n0 = qt * 64;

  // Q fragments (16 rows per wave), scale already folded in
  const u16* qp = qws + ((size_t)((b*NH + h)*1024 + n0 + wid*16 + lc))*64 + lg*8;
  const short8 qf0 = *(const short8*)qp;
  const short8 qf1 = *(const short8*)(qp + 32);

  const u16* bt = btab + (size_t)(h*1024 + n0)*416;
  float pmax[4] = {-3e38f, -3e38f, -3e38f, -3e38f};

  // -------- phase 1: S = q.k^T + bias, chunked over t (128-row K chunks)
  for (int kc = 0; kc < 4; ++kc){
    const int ntt = (kc < 3) ? 8 : 2;               // 416 = 3*128 + 32
    __syncthreads();
    #pragma unroll
    for (int i = 0; i < 4; ++i){
      int lin = tid + i*256;
      if (lin < ntt*16*8){
        int tr = lin >> 3, seg = lin & 7;
        u32x4 d = *(const u32x4*)(Kw + (size_t)(h*NTP + kc*128 + tr)*64 + seg*8);
        int db = (tr*128 + seg*16) ^ ((tr & 7) << 4);
        *(u32x4*)(kvb + db) = d;
      }
    }
    __syncthreads();
    for (int tt = 0; tt < ntt; ++tt){
      int tl = tt*16 + lc;
      int tg = kc*128 + tl;
      short8 kf0 = *(const short8*)(kvb + ((tl*128      + lg*16) ^ ((tl & 7) << 4)));
      short8 kf1 = *(const short8*)(kvb + ((tl*128 + 64 + lg*16) ^ ((tl & 7) << 4)));
      f32x4 a = {0.f, 0.f, 0.f, 0.f};
      a = mfma16(qf0, kf0, a);
      a = mfma16(qf1, kf1, a);
      #pragma unroll
      for (int r = 0; r < 4; ++r){
        int row = wid*16 + lg*4 + r;
        float sv = a[r] + bf2f(bt[(size_t)row*416 + tg]);  // pads carry -1e30
        pmax[r] = fmaxf(pmax[r], sv);
        S[row*SSTR + tg] = f2bf(sv);
      }
    }
  }

  // -------- row max reduce across the 16 t-lanes
  #pragma unroll
  for (int r = 0; r < 4; ++r){
    float p = pmax[r];
    p = fmaxf(p, __shfl_xor(p, 1));
    p = fmaxf(p, __shfl_xor(p, 2));
    p = fmaxf(p, __shfl_xor(p, 4));
    p = fmaxf(p, __shfl_xor(p, 8));
    pmax[r] = p;
  }
  if (lc == 0){
    #pragma unroll
    for (int r = 0; r < 4; ++r) mrow[wid*16 + lg*4 + r] = pmax[r];
  }
  __syncthreads();

  // -------- phase 2: softmax numerator in place, row sums (4 lanes/row)
  {
    const int row = wid*16 + (lane >> 2);
    const int c0 = lane & 3;
    const float m = mrow[row];
    float sum = 0.f;
    u16* Sr = S + row*SSTR;
    for (int k = 0; k < 13; ++k){
      int t0 = c0*8 + k*32;
      short8 sv = *(short8*)(Sr + t0);
      short8 pv;
      #pragma unroll
      for (int j = 0; j < 8; ++j){
        float p = __expf(bf2f((u16)sv[j]) - m);      // pads -> exp(-huge)=0
        sum += p;
        pv[j] = (short)f2bf(p);
      }
      *(short8*)(Sr + t0) = pv;
    }
    sum += __shfl_xor(sum, 1);
    sum += __shfl_xor(sum, 2);
    if (c0 == 0) lrow[row] = sum;
  }

  // -------- phase 3: O = P @ V ; wave covers all 64 rows x its 64 dv cols
  f32x4 acc[4][4] = {};
  for (int vc = 0; vc < 13; ++vc){
    __syncthreads();
    #pragma unroll
    for (int i = 0; i < 4; ++i){
      int lin = tid + i*256;
      int dv = lin >> 2, seg = lin & 3;
      u32x4 d = *(const u32x4*)(Vw + (size_t)(h*256 + dv)*NTP + vc*32 + seg*8);
      int db = (dv*64 + seg*16) ^ ((dv & 7) << 4);
      *(u32x4*)(kvb + db) = d;
    }
    __syncthreads();
    short8 vf[4];
    #pragma unroll
    for (int ct = 0; ct < 4; ++ct){
      int vr = wid*64 + ct*16 + lc;
      vf[ct] = *(const short8*)(kvb + ((vr*64 + lg*16) ^ ((vr & 7) << 4)));
    }
    #pragma unroll
    for (int rt = 0; rt < 4; ++rt){
      short8 pa = *(const short8*)(S + (size_t)(rt*16 + lc)*SSTR + vc*32 + lg*8);
      #pragma unroll
      for (int ct = 0; ct < 4; ++ct)
        acc[rt][ct] = mfma16(pa, vf[ct], acc[rt][ct]);
    }
  }

  // -------- epilogue: /l, exact GELU (A&S 7.1.26 erf), write a_ws bf16
  #pragma unroll
  for (int rt = 0; rt < 4; ++rt){
    #pragma unroll
    for (int r = 0; r < 4; ++r){
      int row = rt*16 + lg*4 + r;
      float linv = 1.0f / lrow[row];
      size_t obase = ((size_t)(bz*1024 + n0 + row))*2048 + h*256;
      #pragma unroll
      for (int ct = 0; ct < 4; ++ct){
        float x = acc[rt][ct][r] * linv;
        float u = x * 0.70710678f;
        float au = fabsf(u);
        float t = 1.0f / (1.0f + 0.3275911f*au);
        float poly = t*(0.254829592f + t*(-0.284496736f + t*(1.421413741f +
                     t*(-1.453152027f + t*1.061405429f))));
        float erfv = 1.0f - poly*__expf(-u*u);
        erfv = (u < 0.f) ? -erfv : erfv;
        float g = 0.5f * x * (1.0f + erfv);
        aws[obase + wid*64 + ct*16 + lc] = f2bf(g);
      }
    }
  }
}

// ---------------------------------------------------------------------------
extern "C" void kernel_launch(void* const* d_in, const int* in_sizes, int n_in,
                              void* d_out, int out_size, void* d_ws, size_t ws_size,
                              hipStream_t stream)
{
  (void)in_sizes; (void)n_in; (void)out_size; (void)ws_size;
  const float* x    = (const float*)d_in[0];
  const float* text = (const float*)d_in[1];
  const float* q_w  = (const float*)d_in[2];
  const float* q_g  = (const float*)d_in[3];
  const float* q_b  = (const float*)d_in[4];
  const float* q_m  = (const float*)d_in[5];
  const float* q_v  = (const float*)d_in[6];
  const float* kv_w = (const float*)d_in[7];
  const float* kv_g = (const float*)d_in[8];
  const float* kv_b = (const float*)d_in[9];
  const float* kv_m = (const float*)d_in[10];
  const float* kv_v = (const float*)d_in[11];
  const float* p_w  = (const float*)d_in[12];
  const float* p_g  = (const float*)d_in[13];
  const float* p_b  = (const float*)d_in[14];
  const float* p_m  = (const float*)d_in[15];
  const float* p_v  = (const float*)d_in[16];
  const float* ab   = (const float*)d_in[17];
  float* out = (float*)d_out;

  char* ws = (char*)d_ws;                 // ~78 MB total
  u16* qwT   = (u16*)(ws + 0);            //  512x512   [N][K]
  u16* kvwT  = (u16*)(ws + 524288);       // 2560x512   [N][K]
  u16* pwT   = (u16*)(ws + 3145728);      //  512x2048  [N][K]
  u16* textb = (u16*)(ws + 5242880);      //  512x512   (rows>=400 zero)
  u16* btab  = (u16*)(ws + 5767168);      //  8x1024x416
  u16* Kw    = (u16*)(ws + 12582912);     //  8x416x64
  u16* Vw    = (u16*)(ws + 13008896);     //  8x256x416 (transposed)
  u16* qws   = (u16*)(ws + 14712832);     //  32x8x1024x64
  u16* aws   = (u16*)(ws + 48267264);     //  8192x2048 (per batch-quarter)

  hipFuncSetAttribute((const void*)attn_kernel,
                      hipFuncAttributeMaxDynamicSharedMemorySize, ATTN_LDS);

  wconv_kernel<<<dim3(8, 8),  256, 0, stream>>>(q_w,  q_g,  q_v,  qwT,  512,  512);
  wconv_kernel<<<dim3(40, 8), 256, 0, stream>>>(kv_w, kv_g, kv_v, kvwT, 512,  2560);
  wconv_kernel<<<dim3(8, 32), 256, 0, stream>>>(p_w,  p_g,  p_v,  pwT,  2048, 512);
  textconv_kernel<<<1024, 256, 0, stream>>>(text, textb);
  bias_kernel<<<13312, 256, 0, stream>>>(ab, btab);

  // kv-proj: M=512(pad) N=2560 K=512
  gemm_kernel<1><<<dim3(20, 4), 256, 0, stream>>>(
      textb, kvwT, kv_g, kv_b, kv_m, kv_v, Kw, Vw, 512, 0);
  // q-proj: M=32768 N=512 K=512
  gemm_kernel<0><<<dim3(4, 256), 256, 0, stream>>>(
      x, qwT, q_g, q_b, q_m, q_v, qws, nullptr, 512, 0);

  for (int q = 0; q < 4; ++q){
    attn_kernel<<<dim3(16, 8, 8), 256, ATTN_LDS, stream>>>(
        qws, Kw, Vw, btab, aws, q*8);
    // proj: M=8192 N=512 K=2048
    gemm_kernel<2><<<dim3(4, 64), 256, 0, stream>>>(
        aws, pwT, p_g, p_b, p_m, p_v, out, nullptr, 2048, q*8192);
  }
}

// Round 2
// 390.820 us; speedup vs baseline: 1.6154x; 1.6154x over previous
//
#include <hip/hip_runtime.h>

// ---------------------------------------------------------------------------
// Attention_81449759801699 on MI355X (gfx950)
// R2: flash-style attention, swapped QK^T (D[t][q]), m=0 softmax (scores
// provably < ~2), P in-reg -> b64 LDS handoff, K/V chunks via global_load_lds
// with pre-swizzled global sources, 2 barriers/chunk, 46 KB LDS.
// GEMMs: m97 128x128 structure; proj runs full-batch when ws allows.
// ---------------------------------------------------------------------------

typedef unsigned short u16;
typedef unsigned int u32;
typedef float  f32x4  __attribute__((ext_vector_type(4)));
typedef float  fl4    __attribute__((ext_vector_type(4)));
typedef short  short8 __attribute__((ext_vector_type(8)));
typedef u32    u32x4  __attribute__((ext_vector_type(4)));
typedef u32    u32x2  __attribute__((ext_vector_type(2)));

#define EPSF 1e-5f
#define NH 8
#define NTP 416                       // 400 text tokens padded to 416 (13*32)

static __device__ __forceinline__ u16 f2bf(float f){
  u32 u = __builtin_bit_cast(u32, f);
  u += 0x7FFFu + ((u >> 16) & 1u);    // RNE (finite inputs only)
  return (u16)(u >> 16);
}
static __device__ __forceinline__ float bf2f(u16 b){
  u32 u = ((u32)b) << 16;
  return __builtin_bit_cast(float, u);
}
static __device__ __forceinline__ float u2f(u32 u){
  return __builtin_bit_cast(float, u);
}
static __device__ __forceinline__ f32x4 mfma16(short8 a, short8 b, f32x4 c){
  return __builtin_amdgcn_mfma_f32_16x16x32_bf16(a, b, c, 0, 0, 0);
}
static __device__ __forceinline__ void gld16(const void* g, void* l){
  __builtin_amdgcn_global_load_lds(
      (const __attribute__((address_space(1))) u32*)g,
      (__attribute__((address_space(3))) u32*)l, 16, 0, 0);
}

// ---------------------------------------------------------------------------
// Weight convert: wT[c][r] = bf16(w[r][c] * gamma[c]*rsqrt(var[c]+eps))
// ---------------------------------------------------------------------------
__global__ __launch_bounds__(256) void wconv_kernel(
    const float* __restrict__ w, const float* __restrict__ gamma,
    const float* __restrict__ var, u16* __restrict__ wT, int R, int C)
{
  __shared__ u16 tile[64*65];
  const int tx = blockIdx.x, ty = blockIdx.y, tid = threadIdx.x;
  #pragma unroll
  for (int i = 0; i < 16; ++i){
    int lin = tid + i*256;
    int rr = lin >> 6, cc = lin & 63;
    int c = tx*64 + cc;
    float s = gamma[c] * rsqrtf(var[c] + EPSF);
    tile[rr*65 + cc] = f2bf(w[(size_t)(ty*64 + rr)*C + c] * s);
  }
  __syncthreads();
  #pragma unroll
  for (int i = 0; i < 16; ++i){
    int lin = tid + i*256;
    int cc = lin >> 6, rr = lin & 63;
    wT[(size_t)(tx*64 + cc)*R + ty*64 + rr] = tile[rr*65 + cc];
  }
}

// text -> bf16, padded to 512 rows (rows >=400 zero)
__global__ __launch_bounds__(256) void textconv_kernel(
    const float* __restrict__ text, u16* __restrict__ tbf)
{
  int idx = blockIdx.x*256 + threadIdx.x;   // 512*512
  int r = idx >> 9, c = idx & 511;
  float v = (r < 400) ? text[r*512 + c] : 0.f;
  tbf[idx] = f2bf(v);
}

// bias table: btab[h][n][t] bf16; t>=400 -> -1e30 (mask)
__global__ __launch_bounds__(256) void bias_kernel(
    const float* __restrict__ ab, u16* __restrict__ btab)
{
  int idx = blockIdx.x*256 + threadIdx.x;   // 8*1024*416
  int t = idx % 416;
  int n = (idx / 416) & 1023;
  int h = idx / (416*1024);
  float v;
  if (t >= 400) v = -1e30f;
  else {
    int i = n >> 5, j = n & 31;
    int a = t / 100, bb = t % 100;
    v = ab[h*10000 + abs(i - a)*100 + abs(j - bb)];
  }
  btab[idx] = f2bf(v);
}

// ---------------------------------------------------------------------------
// 128x128 tile GEMM (m97 structure). BT is [N][K] bf16 (BN scale folded).
// MODE 0: A=x fp32 (reg-stage cvt) -> q_ws[b][h][n][64] bf16, *0.125 folded
// MODE 1: A=text_bf -> K_ws[h][t][64], V_ws[h][dv][t] bf16 (t<416 guard)
// MODE 2: A=a_ws bf16 -> d_out fp32 (+BN shift), rows offset row_base
// ---------------------------------------------------------------------------
template<int MODE>
__global__ __launch_bounds__(256) void gemm_kernel(
    const void* __restrict__ Ap, const u16* __restrict__ BT,
    const float* __restrict__ g1, const float* __restrict__ b1,
    const float* __restrict__ m1, const float* __restrict__ v1,
    void* __restrict__ o0, void* __restrict__ o1, int K, int row_base)
{
  __shared__ u16 lds[8192];                 // A [0,4096), B [4096,8192)
  const int tid = threadIdx.x;
  const int cb = blockIdx.x, rb = blockIdx.y;
  const int lane = tid & 63, wid = tid >> 6;
  const int lg = lane >> 4, lc = lane & 15;
  const int wr = wid >> 1, wc = wid & 1;
  const int row0 = rb*128, col0 = cb*128;
  f32x4 acc[4][4] = {};
  const int nkb = K >> 5;

  for (int kb = 0; kb < nkb; ++kb){
    if (MODE == 0){
      const float* A = (const float*)Ap;
      #pragma unroll
      for (int it = 0; it < 4; ++it){
        int lin = tid + it*256;
        int row = lin >> 3, c4 = lin & 7;
        const fl4 v = *(const fl4*)(A + (size_t)(row0 + row)*K + kb*32 + c4*4);
        u32x2 p;
        p[0] = (u32)f2bf(v[0]) | ((u32)f2bf(v[1]) << 16);
        p[1] = (u32)f2bf(v[2]) | ((u32)f2bf(v[3]) << 16);
        *(u32x2*)&lds[row*32 + c4*4] = p;
      }
    } else {
      const u16* A = (const u16*)Ap;
      #pragma unroll
      for (int it = 0; it < 2; ++it){
        int lin = tid + it*256;
        int row = lin >> 2, seg = lin & 3;
        gld16(A + (size_t)(row0 + row)*K + kb*32 + seg*8, &lds[lin*8]);
      }
    }
    #pragma unroll
    for (int it = 0; it < 2; ++it){
      int lin = tid + it*256;
      int col = lin >> 2, seg = lin & 3;
      gld16(BT + (size_t)(col0 + col)*K + kb*32 + seg*8, &lds[4096 + lin*8]);
    }
    __syncthreads();
    short8 af[4], bfr[4];
    #pragma unroll
    for (int rt = 0; rt < 4; ++rt)
      af[rt] = *(const short8*)&lds[(wr*64 + rt*16 + lc)*32 + lg*8];
    #pragma unroll
    for (int ct = 0; ct < 4; ++ct)
      bfr[ct] = *(const short8*)&lds[4096 + (wc*64 + ct*16 + lc)*32 + lg*8];
    #pragma unroll
    for (int rt = 0; rt < 4; ++rt)
      #pragma unroll
      for (int ct = 0; ct < 4; ++ct)
        acc[rt][ct] = mfma16(af[rt], bfr[ct], acc[rt][ct]);
    __syncthreads();
  }

  if (MODE == 0){
    u16* qws = (u16*)o0;
    #pragma unroll
    for (int ct = 0; ct < 4; ++ct){
      int c = col0 + wc*64 + ct*16 + lc;
      float sc = g1[c] * rsqrtf(v1[c] + EPSF);
      float sh = (b1[c] - m1[c]*sc) * 0.125f;   // 1/sqrt(64) fold
      int h = c >> 6, dk = c & 63;
      #pragma unroll
      for (int rt = 0; rt < 4; ++rt)
        #pragma unroll
        for (int r = 0; r < 4; ++r){
          int mr = row0 + wr*64 + rt*16 + lg*4 + r;
          int b = mr >> 10, n = mr & 1023;
          qws[(size_t)((b*NH + h)*1024 + n)*64 + dk] =
              f2bf(acc[rt][ct][r]*0.125f + sh);
        }
    }
  } else if (MODE == 1){
    u16* Kw = (u16*)o0; u16* Vw = (u16*)o1;
    #pragma unroll
    for (int ct = 0; ct < 4; ++ct){
      int c = col0 + wc*64 + ct*16 + lc;
      float sc = g1[c] * rsqrtf(v1[c] + EPSF);
      float sh = b1[c] - m1[c]*sc;
      int h = c / 320, sub = c % 320;
      #pragma unroll
      for (int rt = 0; rt < 4; ++rt)
        #pragma unroll
        for (int r = 0; r < 4; ++r){
          int t = row0 + wr*64 + rt*16 + lg*4 + r;
          if (t < NTP){
            u16 val = f2bf(acc[rt][ct][r] + sh);
            if (sub < 64) Kw[(size_t)(h*NTP + t)*64 + sub] = val;
            else          Vw[(size_t)(h*256 + (sub - 64))*NTP + t] = val;
          }
        }
    }
  } else {
    float* outp = (float*)o0;
    #pragma unroll
    for (int ct = 0; ct < 4; ++ct){
      int c = col0 + wc*64 + ct*16 + lc;
      float sc = g1[c] * rsqrtf(v1[c] + EPSF);
      float sh = b1[c] - m1[c]*sc;
      #pragma unroll
      for (int rt = 0; rt < 4; ++rt)
        #pragma unroll
        for (int r = 0; r < 4; ++r){
          int mr = row_base + row0 + wr*64 + rt*16 + lg*4 + r;
          outp[(size_t)mr*512 + c] = acc[rt][ct][r] + sh;
        }
    }
  }
}

// ---------------------------------------------------------------------------
// Flash attention, swapped QK^T. Block = 64 q rows x (h, b); 4 waves.
// Wave w: softmax owner of q [16w,16w+16); PV owner of dv [64w,64w+64).
// Chunk = 32 t. K/V double-buffered via global_load_lds (pre-swizzled src).
// m=0 softmax (|scores| << 88, masked pads carry -1e30 bias -> p=0).
// LDS: 40960 (K/V x2) + 5120 (Pbuf, stride 80B) + 256 (lsum) = 46336 B.
// ---------------------------------------------------------------------------
__global__ __launch_bounds__(256) void attn_kernel(
    const u16* __restrict__ qws, const u16* __restrict__ Kw,
    const u16* __restrict__ Vw, const u16* __restrict__ btab,
    u16* __restrict__ aws, int b_base)
{
  __shared__ char kvb[2*20480];     // half: K 4 KB (32t x 128B swz) + V 16 KB (256dv x 64B swz)
  __shared__ char Pb[64*80];        // P bf16 [64 q][32 t], row stride 80 B
  __shared__ float lsum[64];

  const int tid = threadIdx.x;
  const int lane = tid & 63, wid = tid >> 6;
  const int lg = lane >> 4, lc = lane & 15;
  const int qt = blockIdx.x, h = blockIdx.y, bz = blockIdx.z;
  const int b = b_base + bz, n0 = qt*64;

  // Q B-frags (col=q=lc, k=lg*8+j), scale folded at q-proj
  const u16* qp = qws + ((size_t)((b*NH + h)*1024 + n0 + wid*16 + lc))*64 + lg*8;
  const short8 qf0 = *(const short8*)qp;
  const short8 qf1 = *(const short8*)(qp + 32);

  // staging sources: pre-swizzled global addresses so linear gld16 writes
  // land at swizzled LDS slots (K: seg^=t&7; V: dv^=(dv&4)>>2, seg^=dv&3)
  const int kt  = tid >> 3;
  const int ksg = (tid & 7) ^ (kt & 7);
  const u16* ksrc = Kw + ((size_t)h*NTP + kt)*64 + ksg*8;
  const u16* vsrc0, *vsrc1, *vsrc2, *vsrc3;
  {
    const u16* vs[4];
    #pragma unroll
    for (int it = 0; it < 4; ++it){
      int dve = (it*256 + tid) >> 2;
      int dv  = dve ^ ((dve & 4) >> 2);
      int sg  = (tid & 3) ^ (dv & 3);
      vs[it] = Vw + ((size_t)h*256 + dv)*NTP + sg*8;
    }
    vsrc0 = vs[0]; vsrc1 = vs[1]; vsrc2 = vs[2]; vsrc3 = vs[3];
  }
  char* kdst = kvb + wid*1024;          // + half*20480
  char* vdst = kvb + 4096 + wid*1024;   // + half*20480 + it*4096

  const u16* bt = btab + ((size_t)h*1024 + n0 + wid*16 + lc)*416;
  const int swk = (lc & 7) << 4;

  f32x4 acc[4][4] = {};
  float lpart = 0.f;

  // prologue: stage chunk 0 into half 0
  gld16(ksrc, kdst);
  gld16(vsrc0, vdst);
  gld16(vsrc1, vdst + 4096);
  gld16(vsrc2, vdst + 8192);
  gld16(vsrc3, vdst + 12288);

  for (int c = 0; c < 13; ++c){
    const int half = (c & 1) * 20480;
    __syncthreads();                              // B1: stage(c) visible, Pbuf free
    if (c < 12){
      const int nh = ((c + 1) & 1) * 20480;
      gld16(ksrc + (size_t)(c+1)*2048, kdst + nh);
      gld16(vsrc0 + (c+1)*32, vdst + nh);
      gld16(vsrc1 + (c+1)*32, vdst + nh + 4096);
      gld16(vsrc2 + (c+1)*32, vdst + nh + 8192);
      gld16(vsrc3 + (c+1)*32, vdst + nh + 12288);
    }
    // ---- QK^T (swapped): D[t][q] for this wave's 16 q, 32 t
    const char* kb = kvb + half;
    #pragma unroll
    for (int tt = 0; tt < 2; ++tt){
      const int rowb = (tt*16 + lc)*128;
      short8 kf0 = *(const short8*)(kb + rowb + ((lg*16) ^ swk));
      short8 kf1 = *(const short8*)(kb + rowb + ((64 + lg*16) ^ swk));
      u32x2 bb = *(const u32x2*)(bt + c*32 + tt*16 + lg*4);
      f32x4 s;
      s[0] = u2f(bb[0] << 16); s[1] = u2f(bb[0] & 0xffff0000u);
      s[2] = u2f(bb[1] << 16); s[3] = u2f(bb[1] & 0xffff0000u);
      s = mfma16(kf0, qf0, s);
      s = mfma16(kf1, qf1, s);
      float p0 = __expf(s[0]), p1 = __expf(s[1]);
      float p2 = __expf(s[2]), p3 = __expf(s[3]);
      lpart += (p0 + p1) + (p2 + p3);
      u32x2 w;
      w[0] = (u32)f2bf(p0) | ((u32)f2bf(p1) << 16);
      w[1] = (u32)f2bf(p2) | ((u32)f2bf(p3) << 16);
      *(u32x2*)(Pb + (wid*16 + lc)*80 + tt*32 + lg*8) = w;
    }
    __syncthreads();                              // B2: Pbuf ready, stage(c+1) done
    // ---- PV: all 64 q x this wave's 64 dv
    const char* vb = kvb + half + 4096;
    short8 pa[4], vf[4];
    #pragma unroll
    for (int rt = 0; rt < 4; ++rt)
      pa[rt] = *(const short8*)(Pb + (rt*16 + lc)*80 + lg*16);
    #pragma unroll
    for (int ct = 0; ct < 4; ++ct){
      const int dv = wid*64 + ct*16 + lc;
      vf[ct] = *(const short8*)(vb + ((dv*64 + lg*16) ^ ((dv & 7) << 4)));
    }
    #pragma unroll
    for (int rt = 0; rt < 4; ++rt)
      #pragma unroll
      for (int ct = 0; ct < 4; ++ct)
        acc[rt][ct] = mfma16(pa[rt], vf[ct], acc[rt][ct]);
  }

  // ---- row sums -> LDS
  lpart += __shfl_xor(lpart, 16);
  lpart += __shfl_xor(lpart, 32);
  if (lane < 16) lsum[wid*16 + lane] = lpart;
  __syncthreads();

  // ---- epilogue: /l, exact GELU (A&S erf), write aws bf16
  #pragma unroll
  for (int rt = 0; rt < 4; ++rt){
    #pragma unroll
    for (int r = 0; r < 4; ++r){
      const int qrow = rt*16 + lg*4 + r;
      const float linv = 1.0f / lsum[qrow];
      const size_t obase = ((size_t)(bz*1024 + n0 + qrow))*2048 + h*256;
      #pragma unroll
      for (int ct = 0; ct < 4; ++ct){
        float x = acc[rt][ct][r] * linv;
        float u = x * 0.70710678f;
        float au = fabsf(u);
        float t = 1.0f / (1.0f + 0.3275911f*au);
        float poly = t*(0.254829592f + t*(-0.284496736f + t*(1.421413741f +
                     t*(-1.453152027f + t*1.061405429f))));
        float erfv = 1.0f - poly*__expf(-u*u);
        erfv = (u < 0.f) ? -erfv : erfv;
        float g = 0.5f * x * (1.0f + erfv);
        aws[obase + wid*64 + ct*16 + lc] = f2bf(g);
      }
    }
  }
}

// ---------------------------------------------------------------------------
extern "C" void kernel_launch(void* const* d_in, const int* in_sizes, int n_in,
                              void* d_out, int out_size, void* d_ws, size_t ws_size,
                              hipStream_t stream)
{
  (void)in_sizes; (void)n_in; (void)out_size;
  const float* x    = (const float*)d_in[0];
  const float* text = (const float*)d_in[1];
  const float* q_w  = (const float*)d_in[2];
  const float* q_g  = (const float*)d_in[3];
  const float* q_b  = (const float*)d_in[4];
  const float* q_m  = (const float*)d_in[5];
  const float* q_v  = (const float*)d_in[6];
  const float* kv_w = (const float*)d_in[7];
  const float* kv_g = (const float*)d_in[8];
  const float* kv_b = (const float*)d_in[9];
  const float* kv_m = (const float*)d_in[10];
  const float* kv_v = (const float*)d_in[11];
  const float* p_w  = (const float*)d_in[12];
  const float* p_g  = (const float*)d_in[13];
  const float* p_b  = (const float*)d_in[14];
  const float* p_m  = (const float*)d_in[15];
  const float* p_v  = (const float*)d_in[16];
  const float* ab   = (const float*)d_in[17];
  float* out = (float*)d_out;

  char* ws = (char*)d_ws;
  u16* qwT   = (u16*)(ws + 0);            //  512x512   [N][K]
  u16* kvwT  = (u16*)(ws + 524288);       // 2560x512   [N][K]
  u16* pwT   = (u16*)(ws + 3145728);      //  512x2048  [N][K]
  u16* textb = (u16*)(ws + 5242880);      //  512x512
  u16* btab  = (u16*)(ws + 5767168);      //  8x1024x416
  u16* Kw    = (u16*)(ws + 12582912);     //  8x416x64
  u16* Vw    = (u16*)(ws + 13008896);     //  8x256x416 (transposed)
  u16* qws   = (u16*)(ws + 14712832);     //  32x8x1024x64
  u16* aws   = (u16*)(ws + 48267264);     //  32768x2048 (full) or 8192x2048 (quarter)

  const bool full = ws_size >= (size_t)182484992ull;

  wconv_kernel<<<dim3(8, 8),  256, 0, stream>>>(q_w,  q_g,  q_v,  qwT,  512,  512);
  wconv_kernel<<<dim3(40, 8), 256, 0, stream>>>(kv_w, kv_g, kv_v, kvwT, 512,  2560);
  wconv_kernel<<<dim3(8, 32), 256, 0, stream>>>(p_w,  p_g,  p_v,  pwT,  2048, 512);
  textconv_kernel<<<1024, 256, 0, stream>>>(text, textb);
  bias_kernel<<<13312, 256, 0, stream>>>(ab, btab);

  // kv-proj: M=512(pad) N=2560 K=512
  gemm_kernel<1><<<dim3(20, 4), 256, 0, stream>>>(
      textb, kvwT, kv_g, kv_b, kv_m, kv_v, Kw, Vw, 512, 0);
  // q-proj: M=32768 N=512 K=512
  gemm_kernel<0><<<dim3(4, 256), 256, 0, stream>>>(
      x, qwT, q_g, q_b, q_m, q_v, qws, nullptr, 512, 0);

  if (full){
    attn_kernel<<<dim3(16, 8, 32), 256, 0, stream>>>(qws, Kw, Vw, btab, aws, 0);
    // proj: M=32768 N=512 K=2048, 1024 blocks (4/CU)
    gemm_kernel<2><<<dim3(4, 256), 256, 0, stream>>>(
        aws, pwT, p_g, p_b, p_m, p_v, out, nullptr, 2048, 0);
  } else {
    for (int q = 0; q < 4; ++q){
      attn_kernel<<<dim3(16, 8, 8), 256, 0, stream>>>(qws, Kw, Vw, btab, aws, q*8);
      gemm_kernel<2><<<dim3(4, 64), 256, 0, stream>>>(
          aws, pwT, p_g, p_b, p_m, p_v, out, nullptr, 2048, q*8192);
    }
  }
}